// Round 1
// baseline (110.977 us; speedup 1.0000x reference)
//
#include <hip/hip_runtime.h>
#include <math.h>

// Problem constants
#define NH   16
#define HD   64
#define CDIM 1024     // N_EMBD
#define BSZ  8
#define TSZ  64
#define MROWS 512     // B*T
#define LCACHE 4096

// ---------------------------------------------------------------------------
// Kernel 1: compress cached K/V.  Only the first 64 compressed positions per
// (b,h) are ever visible through the causal mask (query i<=63 sees keys j<=i,
// and keys 0..63 are compressed-cache rows 0..63).  One wave per (b,h,lc) row,
// lane = head_dim channel.  conv(stride4,k4) then LayerNorm over d.
// ---------------------------------------------------------------------------
__global__ __launch_bounds__(256)
void compress_kernel(const float* __restrict__ K, const float* __restrict__ V,
                     const float* __restrict__ kc, const float* __restrict__ vc,
                     const float* __restrict__ kg, const float* __restrict__ kb,
                     const float* __restrict__ vg, const float* __restrict__ vb,
                     float* __restrict__ ck, float* __restrict__ cv)
{
    int gid  = blockIdx.x * 256 + threadIdx.x;
    int lane = gid & 63;
    int row  = gid >> 6;        // 0..8191 = bh*64 + lc
    int lc   = row & 63;
    int bh   = row >> 6;        // 0..127

    size_t base = ((size_t)bh * LCACHE + (size_t)lc * 4) * HD + lane;

    float ak = 0.f, av = 0.f;
#pragma unroll
    for (int j = 0; j < 4; ++j) {
        ak = fmaf(K[base + (size_t)j * HD], kc[lane * 4 + j], ak);
        av = fmaf(V[base + (size_t)j * HD], vc[lane * 4 + j], av);
    }

    // LayerNorm over 64 lanes (wave-wide shuffle reduction)
    {
        float s = ak, s2 = ak * ak;
#pragma unroll
        for (int o = 32; o; o >>= 1) { s += __shfl_xor(s, o); s2 += __shfl_xor(s2, o); }
        float mu  = s * (1.f / 64.f);
        float var = s2 * (1.f / 64.f) - mu * mu;
        ck[(size_t)row * HD + lane] = (ak - mu) * rsqrtf(var + 1e-5f) * kg[lane] + kb[lane];
    }
    {
        float s = av, s2 = av * av;
#pragma unroll
        for (int o = 32; o; o >>= 1) { s += __shfl_xor(s, o); s2 += __shfl_xor(s2, o); }
        float mu  = s * (1.f / 64.f);
        float var = s2 * (1.f / 64.f) - mu * mu;
        cv[(size_t)row * HD + lane] = (av - mu) * rsqrtf(var + 1e-5f) * vg[lane] + vb[lane];
    }
}

// ---------------------------------------------------------------------------
// Tiled fp32 GEMM: C[512,1024] = A[512,1024(ld=1024)] @ B[1024, n(ld=ldb)] + bias
// BM=32, BN=64, BK=32, 512 threads, 4 outputs/thread (1 row x 4 cols).
// Grid (16,16) = 256 blocks -> one per CU.
// MODE 0: write to q workspace laid out [b][h][t][d]; MODE 1: direct [m][n].
// ---------------------------------------------------------------------------
template<int MODE>
__global__ __launch_bounds__(512)
void gemm_kernel(const float* __restrict__ A, const float* __restrict__ Bm,
                 const float* __restrict__ bias, float* __restrict__ C, int ldb)
{
    __shared__ float As[32][68];   // transposed: As[k][m], stride 68 (16B aligned, conflict-free)
    __shared__ float Bs[32][68];   // Bs[k][n]

    const int tid  = threadIdx.x;
    const int bx   = blockIdx.x;   // N tile 0..15
    const int by   = blockIdx.y;   // M tile 0..15
    const int tr   = tid >> 4;     // 0..31 : output row within tile
    const int tc   = tid & 15;     // 0..15 : output col group (x4)

    const int lrow = tid >> 4;     // load row 0..31
    const int acol = (tid & 15) * 2;
    const int bcol = (tid & 15) * 4;

    const float* Aptr = A  + (size_t)(by * 32 + lrow) * 1024 + acol;
    const float* Bptr = Bm + (size_t)lrow * ldb + bx * 64 + bcol;

    float acc0 = 0.f, acc1 = 0.f, acc2 = 0.f, acc3 = 0.f;

    for (int kt = 0; kt < 1024; kt += 32) {
        float2 avv = *(const float2*)(Aptr + kt);
        float4 bvv = *(const float4*)(Bptr + (size_t)kt * ldb);
        __syncthreads();                       // protect previous iter's reads
        As[acol + 0][lrow] = avv.x;
        As[acol + 1][lrow] = avv.y;
        *(float4*)&Bs[lrow][bcol] = bvv;
        __syncthreads();
#pragma unroll
        for (int kk = 0; kk < 32; ++kk) {
            float  a = As[kk][tr];                       // 16-lane broadcast
            float4 b = *(const float4*)&Bs[kk][tc * 4];  // 2-way alias = free
            acc0 = fmaf(a, b.x, acc0);
            acc1 = fmaf(a, b.y, acc1);
            acc2 = fmaf(a, b.z, acc2);
            acc3 = fmaf(a, b.w, acc3);
        }
    }

    const int m = by * 32 + tr;        // 0..511
    const int n = bx * 64 + tc * 4;    // 0..1020
    float4 r;
    r.x = acc0 + bias[n + 0];
    r.y = acc1 + bias[n + 1];
    r.z = acc2 + bias[n + 2];
    r.w = acc3 + bias[n + 3];
    if (MODE == 0) {
        // q workspace layout: [b][h][t][d], b=m>>6, t=m&63, h=bx, d=tc*4
        int b = m >> 6, t = m & 63;
        float* dst = C + (((size_t)(b * NH + bx) * TSZ + t) << 6) + tc * 4;
        *(float4*)dst = r;
    } else {
        *(float4*)(C + (size_t)m * 1024 + n) = r;
    }
}

// ---------------------------------------------------------------------------
// Kernel 3: per-(b,h) causal attention, 64 queries x 64 keys x 64 dim.
// Block = (b,h), 1024 threads = 16 waves, each wave owns 4 query rows.
// q, ck, cv staged in LDS with +1 pad (conflict-free).  Softmax via wave
// shuffles; P broadcast via __shfl in the PV loop.
// Writes y in [B][T][C] layout for the output projection.
// ---------------------------------------------------------------------------
__global__ __launch_bounds__(1024)
void attn_kernel(const float* __restrict__ q, const float* __restrict__ ck,
                 const float* __restrict__ cv, float* __restrict__ y)
{
    __shared__ float sq[64][65];
    __shared__ float sk[64][65];
    __shared__ float sv[64][65];

    const int bh  = blockIdx.x;          // 0..127
    const int tid = threadIdx.x;
    const float* qb = q  + (size_t)bh * 4096;
    const float* kp = ck + (size_t)bh * 4096;
    const float* vp = cv + (size_t)bh * 4096;

#pragma unroll
    for (int idx = tid; idx < 4096; idx += 1024) {
        int r = idx >> 6, c = idx & 63;
        sq[r][c] = qb[idx];
        sk[r][c] = kp[idx];
        sv[r][c] = vp[idx];
    }
    __syncthreads();

    const int wave = tid >> 6;
    const int lane = tid & 63;
    const int b = bh >> 4, h = bh & 15;

    for (int i = wave; i < 64; i += 16) {
        // scores: lane = key index j
        float s = 0.f;
#pragma unroll 8
        for (int d = 0; d < 64; ++d)
            s = fmaf(sq[i][d], sk[lane][d], s);
        s *= 0.125f;                       // 1/sqrt(64)
        bool valid = (lane <= i);
        s = valid ? s : -3.0e38f;
        float mx = s;
#pragma unroll
        for (int o = 32; o; o >>= 1) mx = fmaxf(mx, __shfl_xor(mx, o));
        float e = valid ? __expf(s - mx) : 0.f;
        float sum = e;
#pragma unroll
        for (int o = 32; o; o >>= 1) sum += __shfl_xor(sum, o);
        float p = e / sum;

        // y[i][d], lane = d; broadcast p_j from lane j
        float acc = 0.f;
#pragma unroll 8
        for (int j = 0; j < 64; ++j)
            acc = fmaf(__shfl(p, j), sv[j][lane], acc);

        y[((size_t)(b * TSZ + i)) * CDIM + h * HD + lane] = acc;
    }
}

// ---------------------------------------------------------------------------
extern "C" void kernel_launch(void* const* d_in, const int* in_sizes, int n_in,
                              void* d_out, int out_size, void* d_ws, size_t ws_size,
                              hipStream_t stream)
{
    const float* x        = (const float*)d_in[0];
    const float* cached_k = (const float*)d_in[1];
    const float* cached_v = (const float*)d_in[2];
    const float* w_attn   = (const float*)d_in[3];
    const float* b_attn   = (const float*)d_in[4];
    const float* w_proj   = (const float*)d_in[5];
    const float* b_proj   = (const float*)d_in[6];
    const float* k_conv   = (const float*)d_in[7];
    const float* v_conv   = (const float*)d_in[8];
    const float* ln_k_g   = (const float*)d_in[9];
    const float* ln_k_b   = (const float*)d_in[10];
    const float* ln_v_g   = (const float*)d_in[11];
    const float* ln_v_b   = (const float*)d_in[12];

    float* ws   = (float*)d_ws;
    float* q_ws = ws;                    // [8][16][64][64]  = 524288 floats
    float* ck   = ws + 524288;           // [128][64][64]
    float* cv   = ws + 1048576;          // [128][64][64]
    float* y_ws = ws + 1572864;          // [512][1024]
    float* out  = (float*)d_out;         // [512][1024] fp32

    // 1) compress first 64 positions of cached K/V (conv + LN)
    compress_kernel<<<2048, 256, 0, stream>>>(cached_k, cached_v, k_conv, v_conv,
                                              ln_k_g, ln_k_b, ln_v_g, ln_v_b, ck, cv);
    // 2) q projection only (k,v of current tokens are fully masked out)
    gemm_kernel<0><<<dim3(16, 16), 512, 0, stream>>>(x, w_attn, b_attn, q_ws, 3072);
    // 3) 64x64 causal attention per (b,h)
    attn_kernel<<<128, 1024, 0, stream>>>(q_ws, ck, cv, y_ws);
    // 4) output projection
    gemm_kernel<1><<<dim3(16, 16), 512, 0, stream>>>(y_ws, w_proj, b_proj, out, 1024);
}

// Round 2
// 54.402 us; speedup vs baseline: 2.0399x; 2.0399x over previous
//
#include <hip/hip_runtime.h>
#include <math.h>

#define NH   16
#define HD   64
#define CDIM 1024
#define BSZ  8
#define TSZ  64
#define LCACHE 4096

typedef __attribute__((ext_vector_type(8))) short short8;
typedef __attribute__((ext_vector_type(8))) unsigned short ushort8;
typedef __attribute__((ext_vector_type(4))) float f32x4;

__device__ __forceinline__ unsigned short f2bf(float f) {
    unsigned int u = __float_as_uint(f);
    u = (u + 0x7fffu + ((u >> 16) & 1u)) >> 16;   // round-to-nearest-even
    return (unsigned short)u;
}

__device__ __forceinline__ void gload16(const ushort* g, ushort* l) {
    __builtin_amdgcn_global_load_lds((const __attribute__((address_space(1))) void*)g,
                                     (__attribute__((address_space(3))) void*)l, 16, 0, 0);
}

// ---------------------------------------------------------------------------
// Prologue (fused): blocks [0,2048): compress cached K/V (conv+LN, only the
// 64 visible compressed positions per (b,h)).  Blocks [2048,3328): pack
// x -> A-frag layout, w_attn[:, :1024] & w_proj -> B-frag layout, bf16.
// Fragment-linear layout: frag f stored as 64 lanes x 8 bf16 contiguous;
// A frag idx   = (mt*16 + kt)*4 + kb*2 + mb     (mt: 32-row tile, kt: 64-K step)
// B frag idx   = (nt*16 + kt)*8 + kb*4 + nb     (nt: 64-col tile)
// slot mapping: lane l = (ke>>3)*16 + r, j = ke&7  (same bijection both sides)
// ---------------------------------------------------------------------------
__global__ __launch_bounds__(256)
void prologue_kernel(const float* __restrict__ K, const float* __restrict__ V,
                     const float* __restrict__ kcw, const float* __restrict__ vcw,
                     const float* __restrict__ lkg, const float* __restrict__ lkb,
                     const float* __restrict__ lvg, const float* __restrict__ lvb,
                     const float* __restrict__ x,  const float* __restrict__ w_attn,
                     const float* __restrict__ w_proj,
                     float* __restrict__ ck, float* __restrict__ cv,
                     ushort* __restrict__ xp, ushort* __restrict__ wq,
                     ushort* __restrict__ wp)
{
    const int tid = threadIdx.x;
    if (blockIdx.x < 2048) {
        int gid  = blockIdx.x * 256 + tid;
        int lane = gid & 63;
        int row  = gid >> 6;        // bh*64 + lc
        int lc   = row & 63;
        int bh   = row >> 6;
        size_t base = ((size_t)bh * LCACHE + (size_t)lc * 4) * HD + lane;

        float ak = 0.f, av = 0.f;
#pragma unroll
        for (int j = 0; j < 4; ++j) {
            ak = fmaf(K[base + (size_t)j * HD], kcw[lane * 4 + j], ak);
            av = fmaf(V[base + (size_t)j * HD], vcw[lane * 4 + j], av);
        }
        {
            float s = ak, s2 = ak * ak;
#pragma unroll
            for (int o = 32; o; o >>= 1) { s += __shfl_xor(s, o); s2 += __shfl_xor(s2, o); }
            float mu = s * (1.f/64.f), var = s2 * (1.f/64.f) - mu*mu;
            ck[(size_t)row * HD + lane] = (ak - mu) * rsqrtf(var + 1e-5f) * lkg[lane] + lkb[lane];
        }
        {
            float s = av, s2 = av * av;
#pragma unroll
            for (int o = 32; o; o >>= 1) { s += __shfl_xor(s, o); s2 += __shfl_xor(s2, o); }
            float mu = s * (1.f/64.f), var = s2 * (1.f/64.f) - mu*mu;
            cv[(size_t)row * HD + lane] = (av - mu) * rsqrtf(var + 1e-5f) * lvg[lane] + lvb[lane];
        }
        return;
    }

    // ---- pack: one wave per fragment ----
    int f = (blockIdx.x - 2048) * 4 + (tid >> 6);
    int l = tid & 63;
    int r = l & 15, kg8 = l >> 4;     // row-in-frag, k-group
    ushort8 o;
    if (f < 1024) {                   // A-pack: x [512][1024]
        int mt = f >> 6, kt = (f >> 2) & 15, fi = f & 3;
        int kb = fi >> 1, mb = fi & 1;
        int m  = mt * 32 + mb * 16 + r;
        int k0 = kt * 64 + kb * 32 + kg8 * 8;
        const float* s = x + (size_t)m * 1024 + k0;
#pragma unroll
        for (int j = 0; j < 8; ++j) o[j] = f2bf(s[j]);
        *(ushort8*)(xp + (size_t)f * 512 + l * 8) = o;
    } else {                          // B-pack
        int g = f - 1024;
        const float* W; ushort* D; int ldw;
        if (g < 2048) { W = w_attn; D = wq; ldw = 3072; }
        else          { g -= 2048; W = w_proj; D = wp; ldw = 1024; }
        int nt = g >> 7, kt = (g >> 3) & 15, bi = g & 7;
        int kb = bi >> 2, nb = bi & 3;
        int k0 = kt * 64 + kb * 32 + kg8 * 8;
        int n  = nt * 64 + nb * 16 + r;
#pragma unroll
        for (int j = 0; j < 8; ++j) o[j] = f2bf(W[(size_t)(k0 + j) * ldw + n]);
        *(ushort8*)(D + (size_t)g * 512 + l * 8) = o;
    }
}

// ---------------------------------------------------------------------------
// bf16 MFMA GEMM: C[512,1024] = A[512,1024] @ B[1024,1024] + bias
// 32x64 tile, BK=64, 4 waves (256 thr), grid (16,16) = 256 blocks.
// Wave w owns 16-col slice nb=w, 2 row-frags (mb 0,1).  2-phase dbuf with
// width-16 global_load_lds; all LDS reads lane-linear (conflict-free).
// MODE 0: write q [b][h][t][d];  MODE 1: write [m][1024].
// ---------------------------------------------------------------------------
template<int MODE>
__global__ __launch_bounds__(256)
void mfma_gemm(const ushort* __restrict__ Ap, const ushort* __restrict__ Bp,
               const float* __restrict__ bias, float* __restrict__ C)
{
    __shared__ __align__(16) ushort lds[12288];   // 2 x (A 2048 + B 4096)
    const int tid = threadIdx.x;
    const int w = tid >> 6, l = tid & 63;
    const int nt = blockIdx.x;
    const int mt = blockIdx.y;

    const ushort* agb = Ap + (size_t)mt * 32768;   // 16 kt * 2048
    const ushort* bgb = Bp + (size_t)nt * 65536;   // 16 kt * 4096

    f32x4 acc0 = {0.f,0.f,0.f,0.f}, acc1 = {0.f,0.f,0.f,0.f};

#define STAGE(buf, kt) do { \
        const ushort* ga = agb + (kt) * 2048 + w * 512 + l * 8; \
        const ushort* gb = bgb + (kt) * 4096 + w * 1024 + l * 8; \
        ushort* la = &lds[(buf) * 6144 + w * 512]; \
        ushort* lb = &lds[(buf) * 6144 + 2048 + w * 1024]; \
        gload16(ga, la); gload16(gb, lb); gload16(gb + 512, lb + 512); \
    } while (0)

    STAGE(0, 0);
    __syncthreads();
    int cur = 0;
    for (int kt = 0; kt < 16; ++kt) {
        if (kt < 15) STAGE(cur ^ 1, kt + 1);
        const ushort* La = &lds[cur * 6144];
        const ushort* Lb = &lds[cur * 6144 + 2048];
        short8 b0  = *(const short8*)(Lb + (size_t)(0 * 4 + w) * 512 + l * 8);
        short8 a00 = *(const short8*)(La + (size_t)0 * 512 + l * 8);
        short8 a01 = *(const short8*)(La + (size_t)1 * 512 + l * 8);
        acc0 = __builtin_amdgcn_mfma_f32_16x16x32_bf16(a00, b0, acc0, 0, 0, 0);
        acc1 = __builtin_amdgcn_mfma_f32_16x16x32_bf16(a01, b0, acc1, 0, 0, 0);
        short8 b1  = *(const short8*)(Lb + (size_t)(1 * 4 + w) * 512 + l * 8);
        short8 a10 = *(const short8*)(La + (size_t)2 * 512 + l * 8);
        short8 a11 = *(const short8*)(La + (size_t)3 * 512 + l * 8);
        acc0 = __builtin_amdgcn_mfma_f32_16x16x32_bf16(a10, b1, acc0, 0, 0, 0);
        acc1 = __builtin_amdgcn_mfma_f32_16x16x32_bf16(a11, b1, acc1, 0, 0, 0);
        __syncthreads();    // drains vmcnt(0): next-tile stage complete, reads done
        cur ^= 1;
    }
#undef STAGE

    // C/D layout (m89-verified): col = lane&15, row = (lane>>4)*4 + reg
    const int c = l & 15, rg = l >> 4;
    const int n = nt * 64 + w * 16 + c;
    const float bv = bias[n];
#pragma unroll
    for (int mb = 0; mb < 2; ++mb) {
        f32x4 acc = mb ? acc1 : acc0;
#pragma unroll
        for (int rr = 0; rr < 4; ++rr) {
            int m = mt * 32 + mb * 16 + rg * 4 + rr;
            if (MODE == 0) {
                int b = m >> 6, t = m & 63;          // h = nt, d = n&63
                C[(((size_t)(b * NH + nt) * TSZ + t) << 6) + (n & 63)] = acc[rr] + bv;
            } else {
                C[(size_t)m * 1024 + n] = acc[rr] + bv;
            }
        }
    }
}

// ---------------------------------------------------------------------------
// Per-(b,h) causal attention 64x64x64 (fp32).  Output written directly in
// GEMM2's packed-A bf16 fragment layout.
// ---------------------------------------------------------------------------
__global__ __launch_bounds__(1024)
void attn_kernel(const float* __restrict__ q, const float* __restrict__ ck,
                 const float* __restrict__ cv, ushort* __restrict__ yp)
{
    __shared__ float sq[64][65];
    __shared__ float sk[64][65];
    __shared__ float sv[64][65];

    const int bh  = blockIdx.x;          // 0..127
    const int tid = threadIdx.x;
    const float* qb = q  + (size_t)bh * 4096;
    const float* kp = ck + (size_t)bh * 4096;
    const float* vp = cv + (size_t)bh * 4096;

#pragma unroll
    for (int idx = tid; idx < 4096; idx += 1024) {
        int r = idx >> 6, c = idx & 63;
        sq[r][c] = qb[idx];
        sk[r][c] = kp[idx];
        sv[r][c] = vp[idx];
    }
    __syncthreads();

    const int wave = tid >> 6;
    const int lane = tid & 63;
    const int b = bh >> 4, h = bh & 15;

    for (int i = wave; i < 64; i += 16) {
        float s = 0.f;
#pragma unroll 8
        for (int d = 0; d < 64; ++d)
            s = fmaf(sq[i][d], sk[lane][d], s);
        s *= 0.125f;
        bool valid = (lane <= i);
        s = valid ? s : -3.0e38f;
        float mx = s;
#pragma unroll
        for (int o = 32; o; o >>= 1) mx = fmaxf(mx, __shfl_xor(mx, o));
        float e = valid ? __expf(s - mx) : 0.f;
        float sum = e;
#pragma unroll
        for (int o = 32; o; o >>= 1) sum += __shfl_xor(sum, o);
        float p = e / sum;

        float acc = 0.f;
#pragma unroll 8
        for (int j = 0; j < 64; ++j)
            acc = fmaf(__shfl(p, j), sv[j][lane], acc);

        // write y[m = b*64+i][k = h*64+lane] into packed-A layout for GEMM2
        int m   = b * 64 + i;
        int mt  = m >> 5, mb = (m >> 4) & 1, r15 = m & 15;
        int kb  = lane >> 5, ke = lane & 31;
        int l2  = ((ke >> 3) << 4) | r15;
        int j2  = ke & 7;
        size_t off = (size_t)mt * 32768 + (size_t)h * 2048
                   + (size_t)(kb * 2 + mb) * 512 + (size_t)l2 * 8 + j2;
        yp[off] = f2bf(acc);
    }
}

// ---------------------------------------------------------------------------
extern "C" void kernel_launch(void* const* d_in, const int* in_sizes, int n_in,
                              void* d_out, int out_size, void* d_ws, size_t ws_size,
                              hipStream_t stream)
{
    const float* x        = (const float*)d_in[0];
    const float* cached_k = (const float*)d_in[1];
    const float* cached_v = (const float*)d_in[2];
    const float* w_attn   = (const float*)d_in[3];
    const float* b_attn   = (const float*)d_in[4];
    const float* w_proj   = (const float*)d_in[5];
    const float* b_proj   = (const float*)d_in[6];
    const float* k_conv   = (const float*)d_in[7];
    const float* v_conv   = (const float*)d_in[8];
    const float* ln_k_g   = (const float*)d_in[9];
    const float* ln_k_b   = (const float*)d_in[10];
    const float* ln_v_g   = (const float*)d_in[11];
    const float* ln_v_b   = (const float*)d_in[12];

    float* ws    = (float*)d_ws;
    float* q_ws  = ws;                       // 524288 f
    float* ck    = ws + 524288;              // 524288 f
    float* cv    = ws + 1048576;             // 524288 f
    ushort* xp   = (ushort*)(ws + 1572864);  // 524288 u16
    ushort* wq   = xp + 524288;              // 1048576 u16
    ushort* wp   = wq + 1048576;             // 1048576 u16
    ushort* yp   = wp + 1048576;             // 524288 u16
    float* out   = (float*)d_out;

    prologue_kernel<<<3328, 256, 0, stream>>>(cached_k, cached_v, k_conv, v_conv,
                                              ln_k_g, ln_k_b, ln_v_g, ln_v_b,
                                              x, w_attn, w_proj, ck, cv, xp, wq, wp);
    mfma_gemm<0><<<dim3(16, 16), 256, 0, stream>>>(xp, wq, b_attn, q_ws);
    attn_kernel<<<128, 1024, 0, stream>>>(q_ws, ck, cv, yp);
    mfma_gemm<1><<<dim3(16, 16), 256, 0, stream>>>(yp, wp, b_proj, out);
}

// Round 3
// 42.345 us; speedup vs baseline: 2.6208x; 1.2847x over previous
//
#include <hip/hip_runtime.h>
#include <math.h>

#define NH   16
#define HD   64
#define CDIM 1024
#define LCACHE 4096

typedef __attribute__((ext_vector_type(8))) short short8;
typedef __attribute__((ext_vector_type(8))) unsigned short ushort8;
typedef __attribute__((ext_vector_type(4))) float f32x4;

__device__ __forceinline__ unsigned short f2bf(float f) {
    unsigned int u = __float_as_uint(f);
    u = (u + 0x7fffu + ((u >> 16) & 1u)) >> 16;   // round-to-nearest-even
    return (unsigned short)u;
}

__device__ __forceinline__ void gload16(const ushort* g, ushort* l) {
    __builtin_amdgcn_global_load_lds((const __attribute__((address_space(1))) void*)g,
                                     (__attribute__((address_space(3))) void*)l, 16, 0, 0);
}

// ---------------------------------------------------------------------------
// K1: pack x -> A-frag bf16, w_attn[:, :1024] -> wq frags, w_proj -> wp frags.
// Fragment-linear: frag f = 64 lanes x 8 bf16 contiguous (1 KiB).
// A frag idx = (mt*16 + kt)*4 + kb*2 + mb;  B frag idx = (nt*16 + kt)*8 + kb*4 + nb
// slot map: lane l = (ke>>3)*16 + r, j = ke&7  (same bijection for A and B)
// ---------------------------------------------------------------------------
__global__ __launch_bounds__(256)
void pack_kernel(const float* __restrict__ x, const float* __restrict__ w_attn,
                 const float* __restrict__ w_proj,
                 ushort* __restrict__ xp, ushort* __restrict__ wq,
                 ushort* __restrict__ wp)
{
    int f = blockIdx.x * 4 + (threadIdx.x >> 6);   // 0..5119
    int l = threadIdx.x & 63;
    int r = l & 15, kg8 = l >> 4;
    ushort8 o;
    if (f < 1024) {                   // A-pack: x [512][1024]
        int mt = f >> 6, kt = (f >> 2) & 15, fi = f & 3;
        int kb = fi >> 1, mb = fi & 1;
        int m  = mt * 32 + mb * 16 + r;
        int k0 = kt * 64 + kb * 32 + kg8 * 8;
        const float* s = x + (size_t)m * 1024 + k0;
#pragma unroll
        for (int j = 0; j < 8; ++j) o[j] = f2bf(s[j]);
        *(ushort8*)(xp + (size_t)f * 512 + l * 8) = o;
    } else {                          // B-pack
        int g = f - 1024;
        const float* W; ushort* D; int ldw;
        if (g < 2048) { W = w_attn; D = wq; ldw = 3072; }
        else          { g -= 2048; W = w_proj; D = wp; ldw = 1024; }
        int nt = g >> 7, kt = (g >> 3) & 15, bi = g & 7;
        int kb = bi >> 2, nb = bi & 3;
        int k0 = kt * 64 + kb * 32 + kg8 * 8;
        int n  = nt * 64 + nb * 16 + r;
#pragma unroll
        for (int j = 0; j < 8; ++j) o[j] = f2bf(W[(size_t)(k0 + j) * ldw + n]);
        *(ushort8*)(D + (size_t)g * 512 + l * 8) = o;
    }
}

// ---------------------------------------------------------------------------
// K2: fused per (b,h,half):  compress(conv+LN)->LDS  |  q = x@w_attn slice via
// MFMA (split-K, 3-buf counted-vmcnt pipeline)  |  causal attn (fp32, LDS)  |
// write y in packed-A bf16 layout for K3.
// grid 256 (1 block/CU), 512 threads (8 waves).  XCD swizzle: blocks sharing
// an h-slice of w_attn land on the same XCD.
// ---------------------------------------------------------------------------
__global__ __launch_bounds__(512)
void fused_kernel(const float* __restrict__ cached_k, const float* __restrict__ cached_v,
                  const float* __restrict__ kcw, const float* __restrict__ vcw,
                  const float* __restrict__ lkg, const float* __restrict__ lkb,
                  const float* __restrict__ lvg, const float* __restrict__ lvb,
                  const float* __restrict__ b_attn,
                  const ushort* __restrict__ xp, const ushort* __restrict__ wq,
                  ushort* __restrict__ yp)
{
    __shared__ __align__(16) ushort stg[2][3][6144];  // [group][buf][A 2048 + B 4096]
    __shared__ float ck_s[64][65];
    __shared__ float cv_s[64][65];
    __shared__ float qs[32][68];

    const int bid  = blockIdx.x;
    const int h    = ((bid & 7) << 1) | ((bid >> 3) & 1);  // same h -> same XCD
    const int rem  = bid >> 4;
    const int b    = rem >> 1;
    const int half = rem & 1;

    const int tid = threadIdx.x;
    const int w   = tid >> 6;       // 0..7
    const int l   = tid & 63;
    const int kg  = w >> 2;         // split-K group
    const int w4  = w & 3;          // wave-in-group = n-slice

    const int mtA = b * 2 + half;
    const ushort* agb = xp + (size_t)mtA * 32768;
    const ushort* bgb = wq + (size_t)h * 65536;

#define STAGE2(buf, kt) do { \
        const ushort* ga = agb + (size_t)(kt) * 2048 + w4 * 512 + l * 8; \
        const ushort* gb = bgb + (size_t)(kt) * 4096 + w4 * 1024 + l * 8; \
        ushort* la = &stg[kg][buf][w4 * 512]; \
        ushort* lb = &stg[kg][buf][2048 + w4 * 1024]; \
        gload16(ga, la); gload16(gb, lb); gload16(gb + 512, lb + 512); \
    } while (0)

    // issue the first two K-tiles now; they land while compress runs
    STAGE2(0, kg * 8 + 0);
    STAGE2(1, kg * 8 + 1);

    // ---- phase A: compress (conv stride4 k4 + LayerNorm) into LDS ----
    {
        const int NR = half ? 64 : 32;          // key rows this block needs
        float4 wk = *(const float4*)(kcw + l * 4);
        float4 wv = *(const float4*)(vcw + l * 4);
        float gk = lkg[l], bk = lkb[l], gv = lvg[l], bv = lvb[l];
        const float* Kb = cached_k + (size_t)(b * NH + h) * (LCACHE * 64);
        const float* Vb = cached_v + (size_t)(b * NH + h) * (LCACHE * 64);

        for (int t = w; t < 2 * NR; t += 8) {
            bool isK = (t < NR);                 // wave-uniform
            int lc = isK ? t : t - NR;
            const float* src = (isK ? Kb : Vb) + (size_t)lc * 256 + l;
            float4 cw = isK ? wk : wv;
            float a = src[0] * cw.x;
            a = fmaf(src[64],  cw.y, a);
            a = fmaf(src[128], cw.z, a);
            a = fmaf(src[192], cw.w, a);
            float s = a, s2 = a * a;
#pragma unroll
            for (int o = 32; o; o >>= 1) { s += __shfl_xor(s, o); s2 += __shfl_xor(s2, o); }
            float mu  = s * (1.f / 64.f);
            float var = s2 * (1.f / 64.f) - mu * mu;
            float g = isK ? gk : gv, bb = isK ? bk : bv;
            float outv = (a - mu) * rsqrtf(var + 1e-5f) * g + bb;
            (isK ? ck_s : cv_s)[lc][l] = outv;
        }
        if (!half) {                             // zero unused key rows 32..63
            for (int t = w; t < 64; t += 8)
                (t < 32 ? ck_s : cv_s)[32 + (t & 31)][l] = 0.f;
        }
    }

    // ---- phase B: q-tile GEMM (32x64, K=1024, split-K over 2 groups) ----
    f32x4 acc0 = {0.f,0.f,0.f,0.f}, acc1 = {0.f,0.f,0.f,0.f};
#pragma unroll
    for (int s = 0; s < 8; ++s) {
        if (s == 7) asm volatile("s_waitcnt vmcnt(0)" ::: "memory");
        else        asm volatile("s_waitcnt vmcnt(3)" ::: "memory");
        __builtin_amdgcn_s_barrier();
        if (s < 6) STAGE2((s + 2) % 3, kg * 8 + s + 2);
        const ushort* La = &stg[kg][s % 3][0];
        const ushort* Lb = La + 2048;
        short8 b0  = *(const short8*)(Lb + (size_t)w4 * 512 + l * 8);
        short8 a00 = *(const short8*)(La + (size_t)l * 8);
        short8 a01 = *(const short8*)(La + 512 + (size_t)l * 8);
        acc0 = __builtin_amdgcn_mfma_f32_16x16x32_bf16(a00, b0, acc0, 0, 0, 0);
        acc1 = __builtin_amdgcn_mfma_f32_16x16x32_bf16(a01, b0, acc1, 0, 0, 0);
        short8 b1  = *(const short8*)(Lb + (size_t)(4 + w4) * 512 + l * 8);
        short8 a10 = *(const short8*)(La + 1024 + (size_t)l * 8);
        short8 a11 = *(const short8*)(La + 1536 + (size_t)l * 8);
        acc0 = __builtin_amdgcn_mfma_f32_16x16x32_bf16(a10, b1, acc0, 0, 0, 0);
        acc1 = __builtin_amdgcn_mfma_f32_16x16x32_bf16(a11, b1, acc1, 0, 0, 0);
    }
#undef STAGE2

    // reduce split-K partials into qs (group1 adds bias and softmax scale)
    {
        const int c = l & 15, rg = l >> 4;
        const int n = w4 * 16 + c;
        if (kg == 0) {
#pragma unroll
            for (int mb = 0; mb < 2; ++mb) {
                f32x4 acc = mb ? acc1 : acc0;
#pragma unroll
                for (int rr = 0; rr < 4; ++rr)
                    qs[mb * 16 + rg * 4 + rr][n] = acc[rr];
            }
        }
        __syncthreads();
        if (kg == 1) {
            float bv = b_attn[h * 64 + n];
#pragma unroll
            for (int mb = 0; mb < 2; ++mb) {
                f32x4 acc = mb ? acc1 : acc0;
#pragma unroll
                for (int rr = 0; rr < 4; ++rr) {
                    int m = mb * 16 + rg * 4 + rr;
                    qs[m][n] = (qs[m][n] + acc[rr] + bv) * 0.125f;
                }
            }
        }
        __syncthreads();
    }

    // ---- phase C: causal attention, 4 query rows per wave ----
#pragma unroll
    for (int rr = 0; rr < 4; ++rr) {
        const int i  = w * 4 + rr;          // local query row (0..31)
        const int gq = half * 32 + i;       // global query index = mask bound
        float s = 0.f;
#pragma unroll
        for (int d = 0; d < 64; ++d)
            s = fmaf(qs[i][d], ck_s[l][d], s);
        bool valid = (l <= gq);
        s = valid ? s : -3.0e38f;
        float mx = s;
#pragma unroll
        for (int o = 32; o; o >>= 1) mx = fmaxf(mx, __shfl_xor(mx, o));
        float e = valid ? __expf(s - mx) : 0.f;
        float sum = e;
#pragma unroll
        for (int o = 32; o; o >>= 1) sum += __shfl_xor(sum, o);
        float p = e / sum;

        float a0 = 0.f, a1 = 0.f, a2 = 0.f, a3 = 0.f;
#pragma unroll
        for (int j = 0; j < 64; j += 4) {
            a0 = fmaf(__shfl(p, j + 0), cv_s[j + 0][l], a0);
            a1 = fmaf(__shfl(p, j + 1), cv_s[j + 1][l], a1);
            a2 = fmaf(__shfl(p, j + 2), cv_s[j + 2][l], a2);
            a3 = fmaf(__shfl(p, j + 3), cv_s[j + 3][l], a3);
        }
        float acc = (a0 + a1) + (a2 + a3);

        // write y[m = b*64 + gq][col = h*64 + l] in packed-A layout
        int mb2 = i >> 4, r15 = i & 15;
        int kb  = l >> 5, ke = l & 31;
        int l2  = ((ke >> 3) << 4) | r15;
        int j2  = ke & 7;
        size_t off = (size_t)mtA * 32768 + (size_t)h * 2048
                   + (size_t)(kb * 2 + mb2) * 512 + (size_t)l2 * 8 + j2;
        yp[off] = f2bf(acc);
    }
}

// ---------------------------------------------------------------------------
// K3: out = y @ w_proj + b_proj.  32x64 tile, 4 waves, 3-buffer pipeline with
// counted vmcnt (never 0 until tail), raw barriers.  XCD swizzle on nt.
// ---------------------------------------------------------------------------
__global__ __launch_bounds__(256)
void gemm2_kernel(const ushort* __restrict__ Ap, const ushort* __restrict__ Bp,
                  const float* __restrict__ bias, float* __restrict__ C)
{
    __shared__ __align__(16) ushort stg[3][6144];
    const int tid = threadIdx.x;
    const int w = tid >> 6, l = tid & 63;
    const int bid = blockIdx.x;
    const int nt = ((bid & 7) << 1) | ((bid >> 3) & 1);   // same nt -> same XCD
    const int mt = bid >> 4;

    const ushort* agb = Ap + (size_t)mt * 32768;
    const ushort* bgb = Bp + (size_t)nt * 65536;

#define STAGE3(buf, kt) do { \
        const ushort* ga = agb + (size_t)(kt) * 2048 + w * 512 + l * 8; \
        const ushort* gb = bgb + (size_t)(kt) * 4096 + w * 1024 + l * 8; \
        ushort* la = &stg[buf][w * 512]; \
        ushort* lb = &stg[buf][2048 + w * 1024]; \
        gload16(ga, la); gload16(gb, lb); gload16(gb + 512, lb + 512); \
    } while (0)

    STAGE3(0, 0);
    STAGE3(1, 1);

    f32x4 acc0 = {0.f,0.f,0.f,0.f}, acc1 = {0.f,0.f,0.f,0.f};
#pragma unroll
    for (int kt = 0; kt < 16; ++kt) {
        if (kt == 15) asm volatile("s_waitcnt vmcnt(0)" ::: "memory");
        else          asm volatile("s_waitcnt vmcnt(3)" ::: "memory");
        __builtin_amdgcn_s_barrier();
        if (kt < 14) STAGE3((kt + 2) % 3, kt + 2);
        const ushort* La = &stg[kt % 3][0];
        const ushort* Lb = La + 2048;
        short8 b0  = *(const short8*)(Lb + (size_t)w * 512 + l * 8);
        short8 a00 = *(const short8*)(La + (size_t)l * 8);
        short8 a01 = *(const short8*)(La + 512 + (size_t)l * 8);
        acc0 = __builtin_amdgcn_mfma_f32_16x16x32_bf16(a00, b0, acc0, 0, 0, 0);
        acc1 = __builtin_amdgcn_mfma_f32_16x16x32_bf16(a01, b0, acc1, 0, 0, 0);
        short8 b1  = *(const short8*)(Lb + (size_t)(4 + w) * 512 + l * 8);
        short8 a10 = *(const short8*)(La + 1024 + (size_t)l * 8);
        short8 a11 = *(const short8*)(La + 1536 + (size_t)l * 8);
        acc0 = __builtin_amdgcn_mfma_f32_16x16x32_bf16(a10, b1, acc0, 0, 0, 0);
        acc1 = __builtin_amdgcn_mfma_f32_16x16x32_bf16(a11, b1, acc1, 0, 0, 0);
    }
#undef STAGE3

    const int c = l & 15, rg = l >> 4;
    const int n = nt * 64 + w * 16 + c;
    const float bv = bias[n];
#pragma unroll
    for (int mb = 0; mb < 2; ++mb) {
        f32x4 acc = mb ? acc1 : acc0;
#pragma unroll
        for (int rr = 0; rr < 4; ++rr) {
            int m = mt * 32 + mb * 16 + rg * 4 + rr;
            C[(size_t)m * 1024 + n] = acc[rr] + bv;
        }
    }
}

// ---------------------------------------------------------------------------
extern "C" void kernel_launch(void* const* d_in, const int* in_sizes, int n_in,
                              void* d_out, int out_size, void* d_ws, size_t ws_size,
                              hipStream_t stream)
{
    const float* x        = (const float*)d_in[0];
    const float* cached_k = (const float*)d_in[1];
    const float* cached_v = (const float*)d_in[2];
    const float* w_attn   = (const float*)d_in[3];
    const float* b_attn   = (const float*)d_in[4];
    const float* w_proj   = (const float*)d_in[5];
    const float* b_proj   = (const float*)d_in[6];
    const float* k_conv   = (const float*)d_in[7];
    const float* v_conv   = (const float*)d_in[8];
    const float* ln_k_g   = (const float*)d_in[9];
    const float* ln_k_b   = (const float*)d_in[10];
    const float* ln_v_g   = (const float*)d_in[11];
    const float* ln_v_b   = (const float*)d_in[12];

    ushort* xp = (ushort*)d_ws;            // 524288
    ushort* wq = xp + 524288;              // 1048576
    ushort* wp = wq + 1048576;             // 1048576
    ushort* yp = wp + 1048576;             // 524288
    float* out = (float*)d_out;

    pack_kernel<<<1280, 256, 0, stream>>>(x, w_attn, w_proj, xp, wq, wp);
    fused_kernel<<<256, 512, 0, stream>>>(cached_k, cached_v, k_conv, v_conv,
                                          ln_k_g, ln_k_b, ln_v_g, ln_v_b,
                                          b_attn, xp, wq, yp);
    gemm2_kernel<<<256, 256, 0, stream>>>(yp, wp, b_proj, out);
}